// Round 9
// baseline (1284.230 us; speedup 1.0000x reference)
//
#include <hip/hip_runtime.h>

#define B_ 4
#define S_ 4096
#define IN_ 1024
#define H_ 16
#define D_ 64
#define OUT_ 1024
#define HD_ 1024   // H*D
#define M_ 16384   // B*S

typedef __bf16 bf16x8 __attribute__((ext_vector_type(8)));
typedef __bf16 bf16x2 __attribute__((ext_vector_type(2)));
typedef float floatx4 __attribute__((ext_vector_type(4)));
typedef int int32x4 __attribute__((ext_vector_type(4)));

#define TWO_LOG2E 2.885390081777927f   // 2*log2(e)

static __device__ __forceinline__ unsigned int f2bf(float f) {
    unsigned int u = __builtin_bit_cast(unsigned int, f);
    u += 0x7fffu + ((u >> 16) & 1u);   // round-to-nearest-even
    return u >> 16;
}

// ---------------- pipeline flags (zeroed each launch by zero_flags) ---------
// g1cnt[b*32+c]: # of G1 tiles (of 8) done for row-chunk c of batch b.
// scan_done[b*32+c]: # of h-chains (of 16) past chunk c.
__device__ unsigned int g1cnt[128];
__device__ unsigned int scan_done[128];

__global__ void zero_flags() {
    int i = threadIdx.x;
    if (i < 128) { g1cnt[i] = 0; scan_done[i] = 0; }
}

// ---------------- cast fp32 -> bf16, vectorized x4 ----------------
__global__ void cast_f32_bf16(const float* __restrict__ src,
                              unsigned short* __restrict__ dst, int n4) {
    int i = blockIdx.x * blockDim.x + threadIdx.x;
    if (i < n4) {
        float4 v = ((const float4*)src)[i];
        ushort4 o;
        o.x = (unsigned short)f2bf(v.x); o.y = (unsigned short)f2bf(v.y);
        o.z = (unsigned short)f2bf(v.z); o.w = (unsigned short)f2bf(v.w);
        ((ushort4*)dst)[i] = o;
    }
}

// ---------------- 128x128 bf16 MFMA GEMM tile: C = A[M,K] * B[N,K]^T --------
// m97-structure: global_load_lds width=16 into LINEAR [128][32] LDS.
// K = N = 1024 hard-coded. 256 threads.
static __device__ __forceinline__ void gemm_tile(
    const unsigned short* __restrict__ A,
    const unsigned short* __restrict__ Bm,
    float* __restrict__ C,
    int m0, int n0,
    unsigned short* As, unsigned short* Bs) {
    const int t = threadIdx.x;
    const int lane = t & 63;
    const int wave = t >> 6;
    const int wm = wave >> 1, wn = wave & 1;
    const int l16 = lane & 15;
    const int quad = lane >> 4;
    const int r16 = lane >> 2;
    const int kc = lane & 3;

    floatx4 acc[4][4];
#pragma unroll
    for (int i = 0; i < 4; i++)
#pragma unroll
        for (int j = 0; j < 4; j++) acc[i][j] = (floatx4){0.f, 0.f, 0.f, 0.f};

    for (int k0 = 0; k0 < 1024; k0 += 32) {
#pragma unroll
        for (int it = 0; it < 2; it++) {
            int chunk = wave * 2 + it;              // 0..7
            int row = chunk * 16 + r16;
            const unsigned short* ga = A + (size_t)(m0 + row) * 1024 + k0 + kc * 8;
            __builtin_amdgcn_global_load_lds(
                (const __attribute__((address_space(1))) void*)ga,
                (__attribute__((address_space(3))) void*)(As + chunk * 512),
                16, 0, 0);
            const unsigned short* gb = Bm + (size_t)(n0 + row) * 1024 + k0 + kc * 8;
            __builtin_amdgcn_global_load_lds(
                (const __attribute__((address_space(1))) void*)gb,
                (__attribute__((address_space(3))) void*)(Bs + chunk * 512),
                16, 0, 0);
        }
        __syncthreads();
        bf16x8 af[4], bfr[4];
#pragma unroll
        for (int i = 0; i < 4; i++)
            af[i] = *(const bf16x8*)(As + (wm * 64 + i * 16 + l16) * 32 + quad * 8);
#pragma unroll
        for (int j = 0; j < 4; j++)
            bfr[j] = *(const bf16x8*)(Bs + (wn * 64 + j * 16 + l16) * 32 + quad * 8);
#pragma unroll
        for (int i = 0; i < 4; i++)
#pragma unroll
            for (int j = 0; j < 4; j++)
                acc[i][j] = __builtin_amdgcn_mfma_f32_16x16x32_bf16(
                    af[i], bfr[j], acc[i][j], 0, 0, 0);
        __syncthreads();
    }
#pragma unroll
    for (int i = 0; i < 4; i++)
#pragma unroll
        for (int j = 0; j < 4; j++)
#pragma unroll
            for (int r = 0; r < 4; r++) {
                int row = m0 + wm * 64 + i * 16 + quad * 4 + r;
                int col = n0 + wn * 64 + j * 16 + l16;
                C[(size_t)row * 1024 + col] = acc[i][j][r];
            }
}

// ---------------- fused pipeline kernel -------------------------------------
// 256 blocks x 256 threads, 1/CU, all co-resident (trivially within limits).
// blocks 0..63: v11 scan, chunk-gated on g1cnt, publishing scan_done.
// blocks 64..255: 192 workers; work list = 1024 G1 tiles (chunk-major) then
// 1024 G2 tiles (each gated on scan_done==16). d_out doubles as xp scratch;
// G2 overwrites chunk c rows only after scan consumed them (flag-ordered).
__global__ __launch_bounds__(256, 1) void fused(
    const unsigned short* __restrict__ x_bf,
    const unsigned short* __restrict__ win_bf,
    const unsigned short* __restrict__ wout_bf,
    unsigned short* __restrict__ y_bf,
    float* __restrict__ outp,            // d_out: xp scratch -> final out
    const float* __restrict__ w_h,
    const float* __restrict__ bias,
    const float* __restrict__ h0) {
    __shared__ unsigned short As[128 * 32];
    __shared__ unsigned short Bs[128 * 32];
    const int blk = blockIdx.x;

    if (blk >= 64) {
        // ---------------- GEMM worker role ----------------
        const int wid = blk - 64;    // 0..191
        for (int idx = wid; idx < 2048; idx += 192) {
            int j = (idx < 1024) ? idx : idx - 1024;
            int c = j >> 5;              // chunk 0..31
            int b = (j >> 3) & 3;
            int n = j & 7;
            int m0 = (b * 32 + c) * 128;
            int n0 = n * 128;
            if (idx < 1024) {
                gemm_tile(x_bf, win_bf, outp, m0, n0, As, Bs);
                __syncthreads();   // all waves' C stores drained (vmcnt0@barrier)
                if (threadIdx.x == 0)
                    __hip_atomic_fetch_add(&g1cnt[b * 32 + c], 1u,
                                           __ATOMIC_RELEASE, __HIP_MEMORY_SCOPE_AGENT);
            } else {
                if (threadIdx.x == 0) {
                    while (__hip_atomic_load(&scan_done[b * 32 + c],
                                             __ATOMIC_ACQUIRE, __HIP_MEMORY_SCOPE_AGENT) < 16u)
                        __builtin_amdgcn_s_sleep(16);
                }
                __syncthreads();
                gemm_tile(y_bf, wout_bf, outp, m0, n0, As, Bs);
            }
        }
        return;
    }

    // ---------------- scan role (v11 body, chunk-gated) ----------------
    if (threadIdx.x >= 64) return;
    const int bh = blk;
    const int b = bh >> 4;
    const int h = bh & 15;
    const int e = threadIdx.x;
    const int c16 = e & 15;         // fragment column index
    const int q = e >> 4;           // 16-lane group (row)

    auto loadB = [&](int nt, int koff) -> bf16x8 {
        const float* wr = w_h + ((size_t)(h * 64 + nt * 16 + c16)) * 64 + q * 16 + koff;
        float4 v0 = ((const float4*)wr)[0];
        float4 v1 = ((const float4*)wr)[1];
        int32x4 bi;
        bi[0] = (int)(f2bf(v0.x * TWO_LOG2E) | (f2bf(v0.y * TWO_LOG2E) << 16));
        bi[1] = (int)(f2bf(v0.z * TWO_LOG2E) | (f2bf(v0.w * TWO_LOG2E) << 16));
        bi[2] = (int)(f2bf(v1.x * TWO_LOG2E) | (f2bf(v1.y * TWO_LOG2E) << 16));
        bi[3] = (int)(f2bf(v1.z * TWO_LOG2E) | (f2bf(v1.w * TWO_LOG2E) << 16));
        return __builtin_bit_cast(bf16x8, bi);
    };
    const bf16x8 BfA0 = loadB(0, 0), BfB0 = loadB(0, 8);
    const bf16x8 BfA1 = loadB(1, 0), BfB1 = loadB(1, 8);
    const bf16x8 BfA2 = loadB(2, 0), BfB2 = loadB(2, 8);
    const bf16x8 BfA3 = loadB(3, 0), BfB3 = loadB(3, 8);

    const bool q1 = (q & 1) != 0;
    const bool q2 = (q & 2) != 0;

    const float be = bias[h * 64 + e];
    float hn = h0[(b * 16 + h) * 64 + e];

    const float* xb = outp + ((size_t)(b * S_) * 16 + h) * 64 + e;  // xp scratch
    unsigned short* yb = y_bf + ((size_t)(b * S_) * 16 + h) * 64 + e;

    auto waitg1 = [&](int cc) {
        const unsigned int* p = &g1cnt[b * 32 + cc];
        while (__hip_atomic_load(p, __ATOMIC_ACQUIRE, __HIP_MEMORY_SCOPE_AGENT) < 8u)
            __builtin_amdgcn_s_sleep(16);
    };
    waitg1(0);
    waitg1(1);

    float bxA[8], bxB[8];
#pragma unroll
    for (int i2 = 0; i2 < 8; i2++)
        bxA[i2] = (be + xb[(size_t)i2 * 1024]) * TWO_LOG2E;
#pragma unroll
    for (int i2 = 0; i2 < 8; i2++)
        bxB[i2] = (be + xb[(size_t)(8 + i2) * 1024]) * TWO_LOG2E;

    auto step = [&](int t, float bx) {
        float hs = __builtin_bit_cast(float, __builtin_amdgcn_update_dpp(
            0, __builtin_bit_cast(int, hn), 0xF5, 0xF, 0xF, true));
        unsigned int pk;
        asm("v_cvt_pk_bf16_f32 %0, %1, %2" : "=v"(pk) : "v"(hn), "v"(hs));
        int32x4 a0i, a1i;
        a0i[0] = __builtin_amdgcn_update_dpp(0, (int)pk, 0x150 + 0,  0xF, 0xF, true);
        a0i[1] = __builtin_amdgcn_update_dpp(0, (int)pk, 0x150 + 2,  0xF, 0xF, true);
        a0i[2] = __builtin_amdgcn_update_dpp(0, (int)pk, 0x150 + 4,  0xF, 0xF, true);
        a0i[3] = __builtin_amdgcn_update_dpp(0, (int)pk, 0x150 + 6,  0xF, 0xF, true);
        a1i[0] = __builtin_amdgcn_update_dpp(0, (int)pk, 0x150 + 8,  0xF, 0xF, true);
        a1i[1] = __builtin_amdgcn_update_dpp(0, (int)pk, 0x150 + 10, 0xF, 0xF, true);
        a1i[2] = __builtin_amdgcn_update_dpp(0, (int)pk, 0x150 + 12, 0xF, 0xF, true);
        a1i[3] = __builtin_amdgcn_update_dpp(0, (int)pk, 0x150 + 14, 0xF, 0xF, true);
        bf16x8 A0 = __builtin_bit_cast(bf16x8, a0i);
        bf16x8 A1 = __builtin_bit_cast(bf16x8, a1i);
        const floatx4 z4 = (floatx4){0.f, 0.f, 0.f, 0.f};
        const floatx4 cb = (floatx4){bx, 0.f, 0.f, 0.f};
        floatx4 acA0 = __builtin_amdgcn_mfma_f32_16x16x32_bf16(A0, BfA0, cb, 0, 0, 0);
        floatx4 acB0 = __builtin_amdgcn_mfma_f32_16x16x32_bf16(A1, BfB0, z4, 0, 0, 0);
        floatx4 acA1 = __builtin_amdgcn_mfma_f32_16x16x32_bf16(A0, BfA1, cb, 0, 0, 0);
        floatx4 acB1 = __builtin_amdgcn_mfma_f32_16x16x32_bf16(A1, BfB1, z4, 0, 0, 0);
        floatx4 acA2 = __builtin_amdgcn_mfma_f32_16x16x32_bf16(A0, BfA2, cb, 0, 0, 0);
        floatx4 acB2 = __builtin_amdgcn_mfma_f32_16x16x32_bf16(A1, BfB2, z4, 0, 0, 0);
        floatx4 acA3 = __builtin_amdgcn_mfma_f32_16x16x32_bf16(A0, BfA3, cb, 0, 0, 0);
        floatx4 acB3 = __builtin_amdgcn_mfma_f32_16x16x32_bf16(A1, BfB3, z4, 0, 0, 0);
        float yA01 = q1 ? acA1[0] : acA0[0];
        float yA23 = q1 ? acA3[0] : acA2[0];
        float yA   = q2 ? yA23 : yA01;
        float yB01 = q1 ? acB1[0] : acB0[0];
        float yB23 = q1 ? acB3[0] : acB2[0];
        float yB   = q2 ? yB23 : yB01;
        float pre = yA + yB;
        float em = __builtin_amdgcn_exp2f(pre);
        float r  = __builtin_amdgcn_rcpf(em + 1.0f);
        hn = fmaf(-2.0f, r, 1.0f);
        yb[(size_t)t * 1024] = (unsigned short)f2bf(hn);
    };

    for (int cc = 0; cc < 32; cc++) {
        if (cc >= 1 && cc + 1 < 32) waitg1(cc + 1);  // prefetch reads into cc+1
        for (int k = 0; k < 8; k++) {
            int t0 = cc * 128 + k * 16;
#pragma unroll
            for (int u = 0; u < 8; u++) step(t0 + u, bxA[u]);
            if (t0 + 16 < S_) {
#pragma unroll
                for (int i2 = 0; i2 < 8; i2++)
                    bxA[i2] = (be + xb[(size_t)(t0 + 16 + i2) * 1024]) * TWO_LOG2E;
            }
#pragma unroll
            for (int u = 0; u < 8; u++) step(t0 + 8 + u, bxB[u]);
            if (t0 + 24 < S_) {
#pragma unroll
                for (int i2 = 0; i2 < 8; i2++)
                    bxB[i2] = (be + xb[(size_t)(t0 + 24 + i2) * 1024]) * TWO_LOG2E;
            }
        }
        if (e == 0)
            __hip_atomic_fetch_add(&scan_done[b * 32 + cc], 1u,
                                   __ATOMIC_RELEASE, __HIP_MEMORY_SCOPE_AGENT);
    }
}

extern "C" void kernel_launch(void* const* d_in, const int* in_sizes, int n_in,
                              void* d_out, int out_size, void* d_ws, size_t ws_size,
                              hipStream_t stream) {
    const float* x     = (const float*)d_in[0];  // [B,S,IN]
    const float* h0    = (const float*)d_in[1];  // [B,H,D]
    const float* w_in  = (const float*)d_in[2];  // [HD,IN]
    const float* w_h   = (const float*)d_in[3];  // [H,D,D]
    const float* bias  = (const float*)d_in[4];  // [H,D]
    const float* w_out = (const float*)d_in[5];  // [OUT,HD]
    float* out = (float*)d_out;                  // [B,S,OUT] fp32; doubles as xp scratch

    char* ws = (char*)d_ws;
    unsigned short* x_bf    = (unsigned short*)(ws);                       // 33.5 MB
    unsigned short* win_bf  = (unsigned short*)(ws + (size_t)33554432);    // 2 MB
    unsigned short* wout_bf = (unsigned short*)(ws + (size_t)35651584);    // 2 MB
    unsigned short* y_bf    = (unsigned short*)(ws + (size_t)37748736);    // 33.5 MB

    {
        int n4 = (M_ * IN_) / 4;
        cast_f32_bf16<<<(n4 + 255) / 256, 256, 0, stream>>>(x, x_bf, n4);
        int w4 = (HD_ * IN_) / 4;
        cast_f32_bf16<<<(w4 + 255) / 256, 256, 0, stream>>>(w_in, win_bf, w4);
        cast_f32_bf16<<<(w4 + 255) / 256, 256, 0, stream>>>(w_out, wout_bf, w4);
    }
    zero_flags<<<1, 128, 0, stream>>>();
    // one fused pipeline kernel: G1 -> scan -> G2 overlapped via agent-scope flags
    fused<<<256, 256, 0, stream>>>(x_bf, win_bf, wout_bf, y_bf, out, w_h, bias, h0);
}

// Round 10
// 1083.464 us; speedup vs baseline: 1.1853x; 1.1853x over previous
//
#include <hip/hip_runtime.h>

#define B_ 4
#define S_ 4096
#define IN_ 1024
#define H_ 16
#define D_ 64
#define OUT_ 1024
#define HD_ 1024   // H*D
#define M_ 16384   // B*S

typedef __bf16 bf16x8 __attribute__((ext_vector_type(8)));
typedef __bf16 bf16x2 __attribute__((ext_vector_type(2)));
typedef float floatx4 __attribute__((ext_vector_type(4)));
typedef int int32x4 __attribute__((ext_vector_type(4)));

#define TWO_LOG2E 2.885390081777927f   // 2*log2(e)

static __device__ __forceinline__ unsigned int f2bf(float f) {
    unsigned int u = __builtin_bit_cast(unsigned int, f);
    u += 0x7fffu + ((u >> 16) & 1u);   // round-to-nearest-even
    return u >> 16;
}

// scan_done[b*32+c]: # of h-chains (of 16) past chunk c. Zeroed each launch.
__device__ unsigned int scan_done[128];

__global__ void zero_flags() {
    int i = threadIdx.x;
    if (i < 128) scan_done[i] = 0;
}

// ---------------- cast fp32 -> bf16, vectorized x4 ----------------
__global__ void cast_f32_bf16(const float* __restrict__ src,
                              unsigned short* __restrict__ dst, int n4) {
    int i = blockIdx.x * blockDim.x + threadIdx.x;
    if (i < n4) {
        float4 v = ((const float4*)src)[i];
        ushort4 o;
        o.x = (unsigned short)f2bf(v.x); o.y = (unsigned short)f2bf(v.y);
        o.z = (unsigned short)f2bf(v.z); o.w = (unsigned short)f2bf(v.w);
        ((ushort4*)dst)[i] = o;
    }
}

// ---------------- 128x128 bf16 MFMA GEMM tile: C = A[M,K] * B[N,K]^T --------
// m97-structure: global_load_lds width=16 into LINEAR [128][32] LDS.
// K = N = 1024 hard-coded. 256 threads.
static __device__ __forceinline__ void gemm_tile(
    const unsigned short* __restrict__ A,
    const unsigned short* __restrict__ Bm,
    float* __restrict__ C,
    int m0, int n0,
    unsigned short* As, unsigned short* Bs) {
    const int t = threadIdx.x;
    const int lane = t & 63;
    const int wave = t >> 6;
    const int wm = wave >> 1, wn = wave & 1;
    const int l16 = lane & 15;
    const int quad = lane >> 4;
    const int r16 = lane >> 2;
    const int kc = lane & 3;

    floatx4 acc[4][4];
#pragma unroll
    for (int i = 0; i < 4; i++)
#pragma unroll
        for (int j = 0; j < 4; j++) acc[i][j] = (floatx4){0.f, 0.f, 0.f, 0.f};

    for (int k0 = 0; k0 < 1024; k0 += 32) {
#pragma unroll
        for (int it = 0; it < 2; it++) {
            int chunk = wave * 2 + it;              // 0..7
            int row = chunk * 16 + r16;
            const unsigned short* ga = A + (size_t)(m0 + row) * 1024 + k0 + kc * 8;
            __builtin_amdgcn_global_load_lds(
                (const __attribute__((address_space(1))) void*)ga,
                (__attribute__((address_space(3))) void*)(As + chunk * 512),
                16, 0, 0);
            const unsigned short* gb = Bm + (size_t)(n0 + row) * 1024 + k0 + kc * 8;
            __builtin_amdgcn_global_load_lds(
                (const __attribute__((address_space(1))) void*)gb,
                (__attribute__((address_space(3))) void*)(Bs + chunk * 512),
                16, 0, 0);
        }
        __syncthreads();
        bf16x8 af[4], bfr[4];
#pragma unroll
        for (int i = 0; i < 4; i++)
            af[i] = *(const bf16x8*)(As + (wm * 64 + i * 16 + l16) * 32 + quad * 8);
#pragma unroll
        for (int j = 0; j < 4; j++)
            bfr[j] = *(const bf16x8*)(Bs + (wn * 64 + j * 16 + l16) * 32 + quad * 8);
#pragma unroll
        for (int i = 0; i < 4; i++)
#pragma unroll
            for (int j = 0; j < 4; j++)
                acc[i][j] = __builtin_amdgcn_mfma_f32_16x16x32_bf16(
                    af[i], bfr[j], acc[i][j], 0, 0, 0);
        __syncthreads();
    }
#pragma unroll
    for (int i = 0; i < 4; i++)
#pragma unroll
        for (int j = 0; j < 4; j++)
#pragma unroll
            for (int r = 0; r < 4; r++) {
                int row = m0 + wm * 64 + i * 16 + quad * 4 + r;
                int col = n0 + wn * 64 + j * 16 + l16;
                C[(size_t)row * 1024 + col] = acc[i][j][r];
            }
}

// ---------------- standalone GEMM1 (full grid, no flags) --------------------
__global__ __launch_bounds__(256) void gemm_bt(
    const unsigned short* __restrict__ A,
    const unsigned short* __restrict__ Bm,
    float* __restrict__ C) {
    __shared__ unsigned short As[128 * 32];
    __shared__ unsigned short Bs[128 * 32];
    gemm_tile(A, Bm, C, blockIdx.y * 128, blockIdx.x * 128, As, Bs);
}

// ---------------- fused scan + GEMM2 ----------------------------------------
// grid = 64 scan blocks + 1024 G2 blocks, 256 threads each, all co-resident
// (LDS 16KB -> 10 blocks/CU; VGPR ~92 -> not binding). Scan blocks run the
// v11 chain at s_setprio(3) so co-resident G2 waves can't steal issue slots.
// G2 block (b,c,n) gates once on scan_done[b][c]==16 (acquire), then runs
// its tile. d_out aliasing (xp scratch vs final out) is ordered by the flag:
// scan's release-add follows ALL its chunk-c xp reads (vmcnt drained by
// release), so G2's overwrite of out rows chunk c is safe.
__global__ __launch_bounds__(256, 1) void fused(
    const unsigned short* __restrict__ wout_bf,
    unsigned short* __restrict__ y_bf,
    float* __restrict__ outp,            // d_out: xp scratch -> final out
    const float* __restrict__ w_h,
    const float* __restrict__ bias,
    const float* __restrict__ h0) {
    __shared__ unsigned short As[128 * 32];
    __shared__ unsigned short Bs[128 * 32];
    const int blk = blockIdx.x;

    if (blk >= 64) {
        // -------- GEMM2 role: one tile, gated on scan progress --------
        const int j = blk - 64;          // ordered (c, b, n): early chunks first
        const int c = j >> 5;
        const int b = (j >> 3) & 3;
        const int n = j & 7;
        if (threadIdx.x == 0) {
            while (__hip_atomic_load(&scan_done[b * 32 + c],
                                     __ATOMIC_ACQUIRE, __HIP_MEMORY_SCOPE_AGENT) < 16u)
                __builtin_amdgcn_s_sleep(127);   // ~3.4us poll pacing
        }
        __syncthreads();
        gemm_tile(y_bf, wout_bf, outp, (b * 32 + c) * 128, n * 128, As, Bs);
        return;
    }

    // -------- scan role (v11 body, chunk-publishing) --------
    if (threadIdx.x >= 64) return;
    __builtin_amdgcn_s_setprio(3);       // protect the latency chain's issue
    const int b = blk >> 4;
    const int h = blk & 15;
    const int e = threadIdx.x;
    const int c16 = e & 15;
    const int q = e >> 4;

    auto loadB = [&](int nt, int koff) -> bf16x8 {
        const float* wr = w_h + ((size_t)(h * 64 + nt * 16 + c16)) * 64 + q * 16 + koff;
        float4 v0 = ((const float4*)wr)[0];
        float4 v1 = ((const float4*)wr)[1];
        int32x4 bi;
        bi[0] = (int)(f2bf(v0.x * TWO_LOG2E) | (f2bf(v0.y * TWO_LOG2E) << 16));
        bi[1] = (int)(f2bf(v0.z * TWO_LOG2E) | (f2bf(v0.w * TWO_LOG2E) << 16));
        bi[2] = (int)(f2bf(v1.x * TWO_LOG2E) | (f2bf(v1.y * TWO_LOG2E) << 16));
        bi[3] = (int)(f2bf(v1.z * TWO_LOG2E) | (f2bf(v1.w * TWO_LOG2E) << 16));
        return __builtin_bit_cast(bf16x8, bi);
    };
    const bf16x8 BfA0 = loadB(0, 0), BfB0 = loadB(0, 8);
    const bf16x8 BfA1 = loadB(1, 0), BfB1 = loadB(1, 8);
    const bf16x8 BfA2 = loadB(2, 0), BfB2 = loadB(2, 8);
    const bf16x8 BfA3 = loadB(3, 0), BfB3 = loadB(3, 8);

    const bool q1 = (q & 1) != 0;
    const bool q2 = (q & 2) != 0;

    const float be = bias[h * 64 + e];
    float hn = h0[(b * 16 + h) * 64 + e];

    const float* xb = outp + ((size_t)(b * S_) * 16 + h) * 64 + e;   // xp scratch
    unsigned short* yb = y_bf + ((size_t)(b * S_) * 16 + h) * 64 + e;

    float bxA[8], bxB[8];
#pragma unroll
    for (int i2 = 0; i2 < 8; i2++)
        bxA[i2] = (be + xb[(size_t)i2 * 1024]) * TWO_LOG2E;
#pragma unroll
    for (int i2 = 0; i2 < 8; i2++)
        bxB[i2] = (be + xb[(size_t)(8 + i2) * 1024]) * TWO_LOG2E;

    auto step = [&](int t, float bx) {
        float hs = __builtin_bit_cast(float, __builtin_amdgcn_update_dpp(
            0, __builtin_bit_cast(int, hn), 0xF5, 0xF, 0xF, true));
        unsigned int pk;
        asm("v_cvt_pk_bf16_f32 %0, %1, %2" : "=v"(pk) : "v"(hn), "v"(hs));
        int32x4 a0i, a1i;
        a0i[0] = __builtin_amdgcn_update_dpp(0, (int)pk, 0x150 + 0,  0xF, 0xF, true);
        a0i[1] = __builtin_amdgcn_update_dpp(0, (int)pk, 0x150 + 2,  0xF, 0xF, true);
        a0i[2] = __builtin_amdgcn_update_dpp(0, (int)pk, 0x150 + 4,  0xF, 0xF, true);
        a0i[3] = __builtin_amdgcn_update_dpp(0, (int)pk, 0x150 + 6,  0xF, 0xF, true);
        a1i[0] = __builtin_amdgcn_update_dpp(0, (int)pk, 0x150 + 8,  0xF, 0xF, true);
        a1i[1] = __builtin_amdgcn_update_dpp(0, (int)pk, 0x150 + 10, 0xF, 0xF, true);
        a1i[2] = __builtin_amdgcn_update_dpp(0, (int)pk, 0x150 + 12, 0xF, 0xF, true);
        a1i[3] = __builtin_amdgcn_update_dpp(0, (int)pk, 0x150 + 14, 0xF, 0xF, true);
        bf16x8 A0 = __builtin_bit_cast(bf16x8, a0i);
        bf16x8 A1 = __builtin_bit_cast(bf16x8, a1i);
        const floatx4 z4 = (floatx4){0.f, 0.f, 0.f, 0.f};
        const floatx4 cb = (floatx4){bx, 0.f, 0.f, 0.f};
        floatx4 acA0 = __builtin_amdgcn_mfma_f32_16x16x32_bf16(A0, BfA0, cb, 0, 0, 0);
        floatx4 acB0 = __builtin_amdgcn_mfma_f32_16x16x32_bf16(A1, BfB0, z4, 0, 0, 0);
        floatx4 acA1 = __builtin_amdgcn_mfma_f32_16x16x32_bf16(A0, BfA1, cb, 0, 0, 0);
        floatx4 acB1 = __builtin_amdgcn_mfma_f32_16x16x32_bf16(A1, BfB1, z4, 0, 0, 0);
        floatx4 acA2 = __builtin_amdgcn_mfma_f32_16x16x32_bf16(A0, BfA2, cb, 0, 0, 0);
        floatx4 acB2 = __builtin_amdgcn_mfma_f32_16x16x32_bf16(A1, BfB2, z4, 0, 0, 0);
        floatx4 acA3 = __builtin_amdgcn_mfma_f32_16x16x32_bf16(A0, BfA3, cb, 0, 0, 0);
        floatx4 acB3 = __builtin_amdgcn_mfma_f32_16x16x32_bf16(A1, BfB3, z4, 0, 0, 0);
        float yA01 = q1 ? acA1[0] : acA0[0];
        float yA23 = q1 ? acA3[0] : acA2[0];
        float yA   = q2 ? yA23 : yA01;
        float yB01 = q1 ? acB1[0] : acB0[0];
        float yB23 = q1 ? acB3[0] : acB2[0];
        float yB   = q2 ? yB23 : yB01;
        float pre = yA + yB;
        float em = __builtin_amdgcn_exp2f(pre);
        float r  = __builtin_amdgcn_rcpf(em + 1.0f);
        hn = fmaf(-2.0f, r, 1.0f);
        yb[(size_t)t * 1024] = (unsigned short)f2bf(hn);
    };

    for (int cc = 0; cc < 32; cc++) {
        for (int k = 0; k < 8; k++) {
            int t0 = cc * 128 + k * 16;
#pragma unroll
            for (int u = 0; u < 8; u++) step(t0 + u, bxA[u]);
            if (t0 + 16 < S_) {
#pragma unroll
                for (int i2 = 0; i2 < 8; i2++)
                    bxA[i2] = (be + xb[(size_t)(t0 + 16 + i2) * 1024]) * TWO_LOG2E;
            }
#pragma unroll
            for (int u = 0; u < 8; u++) step(t0 + 8 + u, bxB[u]);
            if (t0 + 24 < S_) {
#pragma unroll
                for (int i2 = 0; i2 < 8; i2++)
                    bxB[i2] = (be + xb[(size_t)(t0 + 24 + i2) * 1024]) * TWO_LOG2E;
            }
        }
        if (e == 0)
            __hip_atomic_fetch_add(&scan_done[b * 32 + cc], 1u,
                                   __ATOMIC_RELEASE, __HIP_MEMORY_SCOPE_AGENT);
    }
}

extern "C" void kernel_launch(void* const* d_in, const int* in_sizes, int n_in,
                              void* d_out, int out_size, void* d_ws, size_t ws_size,
                              hipStream_t stream) {
    const float* x     = (const float*)d_in[0];  // [B,S,IN]
    const float* h0    = (const float*)d_in[1];  // [B,H,D]
    const float* w_in  = (const float*)d_in[2];  // [HD,IN]
    const float* w_h   = (const float*)d_in[3];  // [H,D,D]
    const float* bias  = (const float*)d_in[4];  // [H,D]
    const float* w_out = (const float*)d_in[5];  // [OUT,HD]
    float* out = (float*)d_out;                  // [B,S,OUT] fp32; doubles as xp scratch

    char* ws = (char*)d_ws;
    unsigned short* x_bf    = (unsigned short*)(ws);                       // 33.5 MB
    unsigned short* win_bf  = (unsigned short*)(ws + (size_t)33554432);    // 2 MB
    unsigned short* wout_bf = (unsigned short*)(ws + (size_t)35651584);    // 2 MB
    unsigned short* y_bf    = (unsigned short*)(ws + (size_t)37748736);    // 33.5 MB

    {
        int n4 = (M_ * IN_) / 4;
        cast_f32_bf16<<<(n4 + 255) / 256, 256, 0, stream>>>(x, x_bf, n4);
        int w4 = (HD_ * IN_) / 4;
        cast_f32_bf16<<<(w4 + 255) / 256, 256, 0, stream>>>(w_in, win_bf, w4);
        cast_f32_bf16<<<(w4 + 255) / 256, 256, 0, stream>>>(w_out, wout_bf, w4);
    }
    zero_flags<<<1, 128, 0, stream>>>();
    // GEMM1 standalone, full grid (fast; completes before fused starts)
    dim3 g1(HD_ / 128, M_ / 128);
    gemm_bt<<<g1, 256, 0, stream>>>(x_bf, win_bf, out);
    // fused: 64 scan blocks + 1024 flag-gated GEMM2 blocks
    fused<<<64 + 1024, 256, 0, stream>>>(wout_bf, y_bf, out, w_h, bias, h0);
}

// Round 11
// 1010.509 us; speedup vs baseline: 1.2709x; 1.0722x over previous
//
#include <hip/hip_runtime.h>

#define B_ 4
#define S_ 4096
#define IN_ 1024
#define H_ 16
#define D_ 64
#define OUT_ 1024
#define HD_ 1024   // H*D
#define M_ 16384   // B*S

typedef __bf16 bf16x8 __attribute__((ext_vector_type(8)));
typedef __bf16 bf16x2 __attribute__((ext_vector_type(2)));
typedef float floatx4 __attribute__((ext_vector_type(4)));
typedef int int32x4 __attribute__((ext_vector_type(4)));

#define TWO_LOG2E 2.885390081777927f   // 2*log2(e)

static __device__ __forceinline__ unsigned int f2bf(float f) {
    unsigned int u = __builtin_bit_cast(unsigned int, f);
    u += 0x7fffu + ((u >> 16) & 1u);   // round-to-nearest-even
    return u >> 16;
}

// scan_done[b*32+c]: # of h-chains (of 16) past chunk c. Zeroed each launch.
__device__ unsigned int scan_done[128];

__global__ void zero_flags() {
    int i = threadIdx.x;
    if (i < 128) scan_done[i] = 0;
}

// ---------------- cast fp32 -> bf16, vectorized x4 ----------------
__global__ void cast_f32_bf16(const float* __restrict__ src,
                              unsigned short* __restrict__ dst, int n4) {
    int i = blockIdx.x * blockDim.x + threadIdx.x;
    if (i < n4) {
        float4 v = ((const float4*)src)[i];
        ushort4 o;
        o.x = (unsigned short)f2bf(v.x); o.y = (unsigned short)f2bf(v.y);
        o.z = (unsigned short)f2bf(v.z); o.w = (unsigned short)f2bf(v.w);
        ((ushort4*)dst)[i] = o;
    }
}

// ---------------- 128x128 bf16 MFMA GEMM tile: C = A[M,K] * B[N,K]^T --------
// m97-structure: global_load_lds width=16 into LINEAR [128][32] LDS.
// K = N = 1024 hard-coded. 256 threads.
static __device__ __forceinline__ void gemm_tile(
    const unsigned short* __restrict__ A,
    const unsigned short* __restrict__ Bm,
    float* __restrict__ C,
    int m0, int n0,
    unsigned short* As, unsigned short* Bs) {
    const int t = threadIdx.x;
    const int lane = t & 63;
    const int wave = t >> 6;
    const int wm = wave >> 1, wn = wave & 1;
    const int l16 = lane & 15;
    const int quad = lane >> 4;
    const int r16 = lane >> 2;
    const int kc = lane & 3;

    floatx4 acc[4][4];
#pragma unroll
    for (int i = 0; i < 4; i++)
#pragma unroll
        for (int j = 0; j < 4; j++) acc[i][j] = (floatx4){0.f, 0.f, 0.f, 0.f};

    for (int k0 = 0; k0 < 1024; k0 += 32) {
#pragma unroll
        for (int it = 0; it < 2; it++) {
            int chunk = wave * 2 + it;              // 0..7
            int row = chunk * 16 + r16;
            const unsigned short* ga = A + (size_t)(m0 + row) * 1024 + k0 + kc * 8;
            __builtin_amdgcn_global_load_lds(
                (const __attribute__((address_space(1))) void*)ga,
                (__attribute__((address_space(3))) void*)(As + chunk * 512),
                16, 0, 0);
            const unsigned short* gb = Bm + (size_t)(n0 + row) * 1024 + k0 + kc * 8;
            __builtin_amdgcn_global_load_lds(
                (const __attribute__((address_space(1))) void*)gb,
                (__attribute__((address_space(3))) void*)(Bs + chunk * 512),
                16, 0, 0);
        }
        __syncthreads();
        bf16x8 af[4], bfr[4];
#pragma unroll
        for (int i = 0; i < 4; i++)
            af[i] = *(const bf16x8*)(As + (wm * 64 + i * 16 + l16) * 32 + quad * 8);
#pragma unroll
        for (int j = 0; j < 4; j++)
            bfr[j] = *(const bf16x8*)(Bs + (wn * 64 + j * 16 + l16) * 32 + quad * 8);
#pragma unroll
        for (int i = 0; i < 4; i++)
#pragma unroll
            for (int j = 0; j < 4; j++)
                acc[i][j] = __builtin_amdgcn_mfma_f32_16x16x32_bf16(
                    af[i], bfr[j], acc[i][j], 0, 0, 0);
        __syncthreads();
    }
#pragma unroll
    for (int i = 0; i < 4; i++)
#pragma unroll
        for (int j = 0; j < 4; j++)
#pragma unroll
            for (int r = 0; r < 4; r++) {
                int row = m0 + wm * 64 + i * 16 + quad * 4 + r;
                int col = n0 + wn * 64 + j * 16 + l16;
                C[(size_t)row * 1024 + col] = acc[i][j][r];
            }
}

// ---------------- standalone GEMM1 (full grid, no flags) --------------------
__global__ __launch_bounds__(256) void gemm_bt(
    const unsigned short* __restrict__ A,
    const unsigned short* __restrict__ Bm,
    float* __restrict__ C) {
    __shared__ unsigned short As[128 * 32];
    __shared__ unsigned short Bs[128 * 32];
    gemm_tile(A, Bm, C, blockIdx.y * 128, blockIdx.x * 128, As, Bs);
}

// ---------------- fused scan + GEMM2 (v15: CU-isolated) ---------------------
// grid = EXACTLY 256 blocks (= CU count): breadth-first placement gives one
// block per CU, so scan blocks (0..63) share their CU with NOTHING — the R9
// 200us scan slowdown was G2 blocks stacking onto scan CUs (Occupancy 18.5%
// with grid 1088). Blocks 64..255 are 192 persistent G2 workers looping
// chunk-major over the 1024 tiles, each tile gated once on scan_done==16.
// d_out aliasing (xp scratch vs final out) ordered by the release/acquire
// flags exactly as in R9 (passed).
__global__ __launch_bounds__(256, 1) void fused(
    const unsigned short* __restrict__ wout_bf,
    unsigned short* __restrict__ y_bf,
    float* __restrict__ outp,            // d_out: xp scratch -> final out
    const float* __restrict__ w_h,
    const float* __restrict__ bias,
    const float* __restrict__ h0) {
    __shared__ unsigned short As[128 * 32];
    __shared__ unsigned short Bs[128 * 32];
    const int blk = blockIdx.x;

    if (blk >= 64) {
        // -------- GEMM2 worker: ~5.3 tiles, each gated on scan progress -----
        const int wid = blk - 64;        // 0..191
        for (int idx = wid; idx < 1024; idx += 192) {
            const int c = idx >> 5;      // chunk-major: early chunks first
            const int b = (idx >> 3) & 3;
            const int n = idx & 7;
            if (threadIdx.x == 0) {
                while (__hip_atomic_load(&scan_done[b * 32 + c],
                                         __ATOMIC_ACQUIRE, __HIP_MEMORY_SCOPE_AGENT) < 16u)
                    __builtin_amdgcn_s_sleep(127);   // ~3.4us poll pacing
            }
            __syncthreads();
            gemm_tile(y_bf, wout_bf, outp, (b * 32 + c) * 128, n * 128, As, Bs);
            __syncthreads();
        }
        return;
    }

    // -------- scan role (v11 body, chunk-publishing) --------
    if (threadIdx.x >= 64) return;
    __builtin_amdgcn_s_setprio(3);
    const int b = blk >> 4;
    const int h = blk & 15;
    const int e = threadIdx.x;
    const int c16 = e & 15;
    const int q = e >> 4;

    auto loadB = [&](int nt, int koff) -> bf16x8 {
        const float* wr = w_h + ((size_t)(h * 64 + nt * 16 + c16)) * 64 + q * 16 + koff;
        float4 v0 = ((const float4*)wr)[0];
        float4 v1 = ((const float4*)wr)[1];
        int32x4 bi;
        bi[0] = (int)(f2bf(v0.x * TWO_LOG2E) | (f2bf(v0.y * TWO_LOG2E) << 16));
        bi[1] = (int)(f2bf(v0.z * TWO_LOG2E) | (f2bf(v0.w * TWO_LOG2E) << 16));
        bi[2] = (int)(f2bf(v1.x * TWO_LOG2E) | (f2bf(v1.y * TWO_LOG2E) << 16));
        bi[3] = (int)(f2bf(v1.z * TWO_LOG2E) | (f2bf(v1.w * TWO_LOG2E) << 16));
        return __builtin_bit_cast(bf16x8, bi);
    };
    const bf16x8 BfA0 = loadB(0, 0), BfB0 = loadB(0, 8);
    const bf16x8 BfA1 = loadB(1, 0), BfB1 = loadB(1, 8);
    const bf16x8 BfA2 = loadB(2, 0), BfB2 = loadB(2, 8);
    const bf16x8 BfA3 = loadB(3, 0), BfB3 = loadB(3, 8);

    const bool q1 = (q & 1) != 0;
    const bool q2 = (q & 2) != 0;

    const float be = bias[h * 64 + e];
    float hn = h0[(b * 16 + h) * 64 + e];

    const float* xb = outp + ((size_t)(b * S_) * 16 + h) * 64 + e;   // xp scratch
    unsigned short* yb = y_bf + ((size_t)(b * S_) * 16 + h) * 64 + e;

    float bxA[8], bxB[8];
#pragma unroll
    for (int i2 = 0; i2 < 8; i2++)
        bxA[i2] = (be + xb[(size_t)i2 * 1024]) * TWO_LOG2E;
#pragma unroll
    for (int i2 = 0; i2 < 8; i2++)
        bxB[i2] = (be + xb[(size_t)(8 + i2) * 1024]) * TWO_LOG2E;

    auto step = [&](int t, float bx) {
        float hs = __builtin_bit_cast(float, __builtin_amdgcn_update_dpp(
            0, __builtin_bit_cast(int, hn), 0xF5, 0xF, 0xF, true));
        unsigned int pk;
        asm("v_cvt_pk_bf16_f32 %0, %1, %2" : "=v"(pk) : "v"(hn), "v"(hs));
        int32x4 a0i, a1i;
        a0i[0] = __builtin_amdgcn_update_dpp(0, (int)pk, 0x150 + 0,  0xF, 0xF, true);
        a0i[1] = __builtin_amdgcn_update_dpp(0, (int)pk, 0x150 + 2,  0xF, 0xF, true);
        a0i[2] = __builtin_amdgcn_update_dpp(0, (int)pk, 0x150 + 4,  0xF, 0xF, true);
        a0i[3] = __builtin_amdgcn_update_dpp(0, (int)pk, 0x150 + 6,  0xF, 0xF, true);
        a1i[0] = __builtin_amdgcn_update_dpp(0, (int)pk, 0x150 + 8,  0xF, 0xF, true);
        a1i[1] = __builtin_amdgcn_update_dpp(0, (int)pk, 0x150 + 10, 0xF, 0xF, true);
        a1i[2] = __builtin_amdgcn_update_dpp(0, (int)pk, 0x150 + 12, 0xF, 0xF, true);
        a1i[3] = __builtin_amdgcn_update_dpp(0, (int)pk, 0x150 + 14, 0xF, 0xF, true);
        bf16x8 A0 = __builtin_bit_cast(bf16x8, a0i);
        bf16x8 A1 = __builtin_bit_cast(bf16x8, a1i);
        const floatx4 z4 = (floatx4){0.f, 0.f, 0.f, 0.f};
        const floatx4 cb = (floatx4){bx, 0.f, 0.f, 0.f};
        floatx4 acA0 = __builtin_amdgcn_mfma_f32_16x16x32_bf16(A0, BfA0, cb, 0, 0, 0);
        floatx4 acB0 = __builtin_amdgcn_mfma_f32_16x16x32_bf16(A1, BfB0, z4, 0, 0, 0);
        floatx4 acA1 = __builtin_amdgcn_mfma_f32_16x16x32_bf16(A0, BfA1, cb, 0, 0, 0);
        floatx4 acB1 = __builtin_amdgcn_mfma_f32_16x16x32_bf16(A1, BfB1, z4, 0, 0, 0);
        floatx4 acA2 = __builtin_amdgcn_mfma_f32_16x16x32_bf16(A0, BfA2, cb, 0, 0, 0);
        floatx4 acB2 = __builtin_amdgcn_mfma_f32_16x16x32_bf16(A1, BfB2, z4, 0, 0, 0);
        floatx4 acA3 = __builtin_amdgcn_mfma_f32_16x16x32_bf16(A0, BfA3, cb, 0, 0, 0);
        floatx4 acB3 = __builtin_amdgcn_mfma_f32_16x16x32_bf16(A1, BfB3, z4, 0, 0, 0);
        float yA01 = q1 ? acA1[0] : acA0[0];
        float yA23 = q1 ? acA3[0] : acA2[0];
        float yA   = q2 ? yA23 : yA01;
        float yB01 = q1 ? acB1[0] : acB0[0];
        float yB23 = q1 ? acB3[0] : acB2[0];
        float yB   = q2 ? yB23 : yB01;
        float pre = yA + yB;
        float em = __builtin_amdgcn_exp2f(pre);
        float r  = __builtin_amdgcn_rcpf(em + 1.0f);
        hn = fmaf(-2.0f, r, 1.0f);
        yb[(size_t)t * 1024] = (unsigned short)f2bf(hn);
    };

    for (int cc = 0; cc < 32; cc++) {
        for (int k = 0; k < 8; k++) {
            int t0 = cc * 128 + k * 16;
#pragma unroll
            for (int u = 0; u < 8; u++) step(t0 + u, bxA[u]);
            if (t0 + 16 < S_) {
#pragma unroll
                for (int i2 = 0; i2 < 8; i2++)
                    bxA[i2] = (be + xb[(size_t)(t0 + 16 + i2) * 1024]) * TWO_LOG2E;
            }
#pragma unroll
            for (int u = 0; u < 8; u++) step(t0 + 8 + u, bxB[u]);
            if (t0 + 24 < S_) {
#pragma unroll
                for (int i2 = 0; i2 < 8; i2++)
                    bxB[i2] = (be + xb[(size_t)(t0 + 24 + i2) * 1024]) * TWO_LOG2E;
            }
        }
        if (e == 0)
            __hip_atomic_fetch_add(&scan_done[b * 32 + cc], 1u,
                                   __ATOMIC_RELEASE, __HIP_MEMORY_SCOPE_AGENT);
    }
}

extern "C" void kernel_launch(void* const* d_in, const int* in_sizes, int n_in,
                              void* d_out, int out_size, void* d_ws, size_t ws_size,
                              hipStream_t stream) {
    const float* x     = (const float*)d_in[0];  // [B,S,IN]
    const float* h0    = (const float*)d_in[1];  // [B,H,D]
    const float* w_in  = (const float*)d_in[2];  // [HD,IN]
    const float* w_h   = (const float*)d_in[3];  // [H,D,D]
    const float* bias  = (const float*)d_in[4];  // [H,D]
    const float* w_out = (const float*)d_in[5];  // [OUT,HD]
    float* out = (float*)d_out;                  // [B,S,OUT] fp32; doubles as xp scratch

    char* ws = (char*)d_ws;
    unsigned short* x_bf    = (unsigned short*)(ws);                       // 33.5 MB
    unsigned short* win_bf  = (unsigned short*)(ws + (size_t)33554432);    // 2 MB
    unsigned short* wout_bf = (unsigned short*)(ws + (size_t)35651584);    // 2 MB
    unsigned short* y_bf    = (unsigned short*)(ws + (size_t)37748736);    // 33.5 MB

    {
        int n4 = (M_ * IN_) / 4;
        cast_f32_bf16<<<(n4 + 255) / 256, 256, 0, stream>>>(x, x_bf, n4);
        int w4 = (HD_ * IN_) / 4;
        cast_f32_bf16<<<(w4 + 255) / 256, 256, 0, stream>>>(w_in, win_bf, w4);
        cast_f32_bf16<<<(w4 + 255) / 256, 256, 0, stream>>>(w_out, wout_bf, w4);
    }
    zero_flags<<<1, 128, 0, stream>>>();
    // GEMM1 standalone, full grid (fast; completes before fused starts)
    dim3 g1(HD_ / 128, M_ / 128);
    gemm_bt<<<g1, 256, 0, stream>>>(x_bf, win_bf, out);
    // fused: 64 scan blocks + 192 persistent G2 workers, 256 blocks = 1/CU
    fused<<<256, 256, 0, stream>>>(wout_bf, y_bf, out, w_h, bias, h0);
}

// Round 12
// 941.622 us; speedup vs baseline: 1.3638x; 1.0732x over previous
//
#include <hip/hip_runtime.h>

#define B_ 4
#define S_ 4096
#define IN_ 1024
#define H_ 16
#define D_ 64
#define OUT_ 1024
#define HD_ 1024   // H*D
#define M_ 16384   // B*S

typedef __bf16 bf16x8 __attribute__((ext_vector_type(8)));
typedef __bf16 bf16x2 __attribute__((ext_vector_type(2)));
typedef float floatx4 __attribute__((ext_vector_type(4)));
typedef int int32x4 __attribute__((ext_vector_type(4)));

#define TWO_LOG2E 2.885390081777927f   // 2*log2(e)

static __device__ __forceinline__ unsigned int f2bf(float f) {
    unsigned int u = __builtin_bit_cast(unsigned int, f);
    u += 0x7fffu + ((u >> 16) & 1u);   // round-to-nearest-even
    return u >> 16;
}

// ---------------- cast fp32 -> bf16, vectorized x4 ----------------
__global__ void cast_f32_bf16(const float* __restrict__ src,
                              unsigned short* __restrict__ dst, int n4) {
    int i = blockIdx.x * blockDim.x + threadIdx.x;
    if (i < n4) {
        float4 v = ((const float4*)src)[i];
        ushort4 o;
        o.x = (unsigned short)f2bf(v.x); o.y = (unsigned short)f2bf(v.y);
        o.z = (unsigned short)f2bf(v.z); o.w = (unsigned short)f2bf(v.w);
        ((ushort4*)dst)[i] = o;
    }
}

// ---------------- bf16 MFMA GEMM: C[M,N] = A[M,K] * B[N,K]^T ----------------
// m97-structure staging (global_load_lds width=16, linear [128][32] LDS) +
// T1 XCD swizzle: 1D grid 1024, swz=(bid&7)*128+(bid>>3) gives XCD a the
// 128 contiguous tiles [128a,128a+128) = 16 complete row-panels, col-tile
// fastest. Working set per XCD = one 256KB A-panel + 2MB B -> L2-resident;
// kills the ~8x A-panel re-fetch of the default x-fastest round-robin
// placement (the real binder; staging swap in R6 was null for this reason).
__global__ __launch_bounds__(256) void gemm_bt(
    const unsigned short* __restrict__ A,   // [16384,1024] bf16
    const unsigned short* __restrict__ Bm,  // [1024,1024] bf16
    float* __restrict__ C) {                // [16384,1024] fp32
    __shared__ unsigned short As[128 * 32];
    __shared__ unsigned short Bs[128 * 32];
    const int bid = blockIdx.x;
    const int swz = (bid & 7) * 128 + (bid >> 3);   // bijective, 1024 blocks
    const int m0 = (swz >> 3) * 128;
    const int n0 = (swz & 7) * 128;

    const int t = threadIdx.x;
    const int lane = t & 63;
    const int wave = t >> 6;
    const int wm = wave >> 1, wn = wave & 1;
    const int l16 = lane & 15;
    const int quad = lane >> 4;
    const int r16 = lane >> 2;      // row within 16-row chunk
    const int kc = lane & 3;        // 8-ushort k-slot within row

    floatx4 acc[4][4];
#pragma unroll
    for (int i = 0; i < 4; i++)
#pragma unroll
        for (int j = 0; j < 4; j++) acc[i][j] = (floatx4){0.f, 0.f, 0.f, 0.f};

    for (int k0 = 0; k0 < 1024; k0 += 32) {
#pragma unroll
        for (int it = 0; it < 2; it++) {
            int chunk = wave * 2 + it;              // 0..7
            int row = chunk * 16 + r16;
            const unsigned short* ga = A + (size_t)(m0 + row) * 1024 + k0 + kc * 8;
            __builtin_amdgcn_global_load_lds(
                (const __attribute__((address_space(1))) void*)ga,
                (__attribute__((address_space(3))) void*)(As + chunk * 512),
                16, 0, 0);
            const unsigned short* gb = Bm + (size_t)(n0 + row) * 1024 + k0 + kc * 8;
            __builtin_amdgcn_global_load_lds(
                (const __attribute__((address_space(1))) void*)gb,
                (__attribute__((address_space(3))) void*)(Bs + chunk * 512),
                16, 0, 0);
        }
        __syncthreads();
        bf16x8 af[4], bfr[4];
#pragma unroll
        for (int i = 0; i < 4; i++)
            af[i] = *(const bf16x8*)(As + (wm * 64 + i * 16 + l16) * 32 + quad * 8);
#pragma unroll
        for (int j = 0; j < 4; j++)
            bfr[j] = *(const bf16x8*)(Bs + (wn * 64 + j * 16 + l16) * 32 + quad * 8);
#pragma unroll
        for (int i = 0; i < 4; i++)
#pragma unroll
            for (int j = 0; j < 4; j++)
                acc[i][j] = __builtin_amdgcn_mfma_f32_16x16x32_bf16(
                    af[i], bfr[j], acc[i][j], 0, 0, 0);
        __syncthreads();
    }
#pragma unroll
    for (int i = 0; i < 4; i++)
#pragma unroll
        for (int j = 0; j < 4; j++)
#pragma unroll
            for (int r = 0; r < 4; r++) {
                int row = m0 + wm * 64 + i * 16 + quad * 4 + r;
                int col = n0 + wn * 64 + j * 16 + l16;
                C[(size_t)row * 1024 + col] = acc[i][j][r];
            }
}

// ---------------- sequential RNN scan (v11: short-chain step) ---------------
// 64 blocks (one (b,h) chain), ONE wave, 1 wave/CU. 415 cyc/step measured;
// practical floor for this structure (4 rounds of layer-shaving hit
// diminishing returns; store-batching and multi-wave variants regressed).
__global__ __launch_bounds__(64, 1) void rnn_scan(
    const float* __restrict__ xp,      // [B,S,H,D] fp32 (GEMM1 output)
    const float* __restrict__ w_h,     // [H,D,D]
    const float* __restrict__ bias,    // [H,D]
    const float* __restrict__ h0,      // [B,H,D]
    unsigned short* __restrict__ y) {  // [B,S,H,D] bf16
    const int bh = blockIdx.x;
    const int b = bh >> 4;
    const int h = bh & 15;
    const int e = threadIdx.x;
    const int c = e & 15;           // fragment column index
    const int q = e >> 4;           // 16-lane group (row)

    // static W^T B-fragments under pi (group q supplies h[16q..16q+15]),
    // scaled by 2*log2e.
    auto loadB = [&](int nt, int koff) -> bf16x8 {
        const float* wr = w_h + ((size_t)(h * 64 + nt * 16 + c)) * 64 + q * 16 + koff;
        float4 v0 = ((const float4*)wr)[0];
        float4 v1 = ((const float4*)wr)[1];
        int32x4 bi;
        bi[0] = (int)(f2bf(v0.x * TWO_LOG2E) | (f2bf(v0.y * TWO_LOG2E) << 16));
        bi[1] = (int)(f2bf(v0.z * TWO_LOG2E) | (f2bf(v0.w * TWO_LOG2E) << 16));
        bi[2] = (int)(f2bf(v1.x * TWO_LOG2E) | (f2bf(v1.y * TWO_LOG2E) << 16));
        bi[3] = (int)(f2bf(v1.z * TWO_LOG2E) | (f2bf(v1.w * TWO_LOG2E) << 16));
        return __builtin_bit_cast(bf16x8, bi);
    };
    const bf16x8 BfA0 = loadB(0, 0), BfB0 = loadB(0, 8);
    const bf16x8 BfA1 = loadB(1, 0), BfB1 = loadB(1, 8);
    const bf16x8 BfA2 = loadB(2, 0), BfB2 = loadB(2, 8);
    const bf16x8 BfA3 = loadB(3, 0), BfB3 = loadB(3, 8);

    const bool q1 = (q & 1) != 0;
    const bool q2 = (q & 2) != 0;

    const float be = bias[h * 64 + e];
    float hn = h0[(b * 16 + h) * 64 + e];   // f32 state, 1/lane

    const float* xb = xp + ((size_t)(b * S_) * 16 + h) * 64 + e;  // + t*1024
    unsigned short* yb = y + ((size_t)(b * S_) * 16 + h) * 64 + e;

    float bxA[8], bxB[8];
#pragma unroll
    for (int i2 = 0; i2 < 8; i2++)
        bxA[i2] = (be + xb[(size_t)i2 * 1024]) * TWO_LOG2E;
#pragma unroll
    for (int i2 = 0; i2 < 8; i2++)
        bxB[i2] = (be + xb[(size_t)(8 + i2) * 1024]) * TWO_LOG2E;

    auto step = [&](int t, float bx) {
        float hs = __builtin_bit_cast(float, __builtin_amdgcn_update_dpp(
            0, __builtin_bit_cast(int, hn), 0xF5, 0xF, 0xF, true));
        unsigned int pk;
        asm("v_cvt_pk_bf16_f32 %0, %1, %2" : "=v"(pk) : "v"(hn), "v"(hs));
        int32x4 a0i, a1i;
        a0i[0] = __builtin_amdgcn_update_dpp(0, (int)pk, 0x150 + 0,  0xF, 0xF, true);
        a0i[1] = __builtin_amdgcn_update_dpp(0, (int)pk, 0x150 + 2,  0xF, 0xF, true);
        a0i[2] = __builtin_amdgcn_update_dpp(0, (int)pk, 0x150 + 4,  0xF, 0xF, true);
        a0i[3] = __builtin_amdgcn_update_dpp(0, (int)pk, 0x150 + 6,  0xF, 0xF, true);
        a1i[0] = __builtin_amdgcn_update_dpp(0, (int)pk, 0x150 + 8,  0xF, 0xF, true);
        a1i[1] = __builtin_amdgcn_update_dpp(0, (int)pk, 0x150 + 10, 0xF, 0xF, true);
        a1i[2] = __builtin_amdgcn_update_dpp(0, (int)pk, 0x150 + 12, 0xF, 0xF, true);
        a1i[3] = __builtin_amdgcn_update_dpp(0, (int)pk, 0x150 + 14, 0xF, 0xF, true);
        bf16x8 A0 = __builtin_bit_cast(bf16x8, a0i);   // h[16q + 0..7]
        bf16x8 A1 = __builtin_bit_cast(bf16x8, a1i);   // h[16q + 8..15]
        const floatx4 z4 = (floatx4){0.f, 0.f, 0.f, 0.f};
        const floatx4 cb = (floatx4){bx, 0.f, 0.f, 0.f};
        floatx4 acA0 = __builtin_amdgcn_mfma_f32_16x16x32_bf16(A0, BfA0, cb, 0, 0, 0);
        floatx4 acB0 = __builtin_amdgcn_mfma_f32_16x16x32_bf16(A1, BfB0, z4, 0, 0, 0);
        floatx4 acA1 = __builtin_amdgcn_mfma_f32_16x16x32_bf16(A0, BfA1, cb, 0, 0, 0);
        floatx4 acB1 = __builtin_amdgcn_mfma_f32_16x16x32_bf16(A1, BfB1, z4, 0, 0, 0);
        floatx4 acA2 = __builtin_amdgcn_mfma_f32_16x16x32_bf16(A0, BfA2, cb, 0, 0, 0);
        floatx4 acB2 = __builtin_amdgcn_mfma_f32_16x16x32_bf16(A1, BfB2, z4, 0, 0, 0);
        floatx4 acA3 = __builtin_amdgcn_mfma_f32_16x16x32_bf16(A0, BfA3, cb, 0, 0, 0);
        floatx4 acB3 = __builtin_amdgcn_mfma_f32_16x16x32_bf16(A1, BfB3, z4, 0, 0, 0);
        float yA01 = q1 ? acA1[0] : acA0[0];
        float yA23 = q1 ? acA3[0] : acA2[0];
        float yA   = q2 ? yA23 : yA01;
        float yB01 = q1 ? acB1[0] : acB0[0];
        float yB23 = q1 ? acB3[0] : acB2[0];
        float yB   = q2 ? yB23 : yB01;
        float pre = yA + yB;                       // = 2*log2e * preact
        float em = __builtin_amdgcn_exp2f(pre);
        float r  = __builtin_amdgcn_rcpf(em + 1.0f);
        hn = fmaf(-2.0f, r, 1.0f);
        yb[(size_t)t * 1024] = (unsigned short)f2bf(hn);
    };

    for (int t0 = 0; t0 < S_; t0 += 16) {
#pragma unroll
        for (int u = 0; u < 8; u++) step(t0 + u, bxA[u]);
        if (t0 + 16 < S_) {
#pragma unroll
            for (int i2 = 0; i2 < 8; i2++)
                bxA[i2] = (be + xb[(size_t)(t0 + 16 + i2) * 1024]) * TWO_LOG2E;
        }
#pragma unroll
        for (int u = 0; u < 8; u++) step(t0 + 8 + u, bxB[u]);
        if (t0 + 24 < S_) {
#pragma unroll
            for (int i2 = 0; i2 < 8; i2++)
                bxB[i2] = (be + xb[(size_t)(t0 + 24 + i2) * 1024]) * TWO_LOG2E;
        }
    }
}

extern "C" void kernel_launch(void* const* d_in, const int* in_sizes, int n_in,
                              void* d_out, int out_size, void* d_ws, size_t ws_size,
                              hipStream_t stream) {
    const float* x     = (const float*)d_in[0];  // [B,S,IN]
    const float* h0    = (const float*)d_in[1];  // [B,H,D]
    const float* w_in  = (const float*)d_in[2];  // [HD,IN]
    const float* w_h   = (const float*)d_in[3];  // [H,D,D]
    const float* bias  = (const float*)d_in[4];  // [H,D]
    const float* w_out = (const float*)d_in[5];  // [OUT,HD]
    float* out = (float*)d_out;                  // [B,S,OUT] fp32; doubles as xp scratch

    char* ws = (char*)d_ws;
    unsigned short* x_bf    = (unsigned short*)(ws);                       // 33.5 MB
    unsigned short* win_bf  = (unsigned short*)(ws + (size_t)33554432);    // 2 MB
    unsigned short* wout_bf = (unsigned short*)(ws + (size_t)35651584);    // 2 MB
    unsigned short* y_bf    = (unsigned short*)(ws + (size_t)37748736);    // 33.5 MB

    {
        int n4 = (M_ * IN_) / 4;
        cast_f32_bf16<<<(n4 + 255) / 256, 256, 0, stream>>>(x, x_bf, n4);
        int w4 = (HD_ * IN_) / 4;
        cast_f32_bf16<<<(w4 + 255) / 256, 256, 0, stream>>>(w_in, win_bf, w4);
        cast_f32_bf16<<<(w4 + 255) / 256, 256, 0, stream>>>(w_out, wout_bf, w4);
    }
    // GEMM1: xp = x @ w_in^T -> d_out scratch (T1 XCD-swizzled 1D grid)
    gemm_bt<<<1024, 256, 0, stream>>>(x_bf, win_bf, out);
    // sequential scan: reads xp (d_out), writes y_bf (64 chains, 1 wave/CU)
    rnn_scan<<<64, 64, 0, stream>>>(out, w_h, bias, h0, y_bf);
    // GEMM2: out = y @ w_out^T -> overwrites d_out
    gemm_bt<<<1024, 256, 0, stream>>>(y_bf, wout_bf, out);
}